// Round 12
// baseline (1813.325 us; speedup 1.0000x reference)
//
#include <hip/hip_runtime.h>
#include <stdint.h>

#define N_NODES 100000
#define N_EDGES 1600000

// Round 12. Resolution of the 9-round NaN mystery: inputs AND outputs are FP32
// (as the reference says). Evidence: K2 (the only near-pass, 0.2656) was the
// only dtype-ADAPTIVE round (inputs + outputs); K4's weird finite 3.33 exactly
// matches "bf16-written buffer read as fp32 == take odd-indexed bf16s" since
// bf16 is the high half of fp32; all 9 hardcoded-bf16 rounds NaN'd via
// exponent-0xFF decode of fp32 mantissa halves (+Inf survives fmaxf ReLU).
// This kernel is dual-world: k_detect (proven in K2) picks bf16 vs fp32 at
// runtime; every kernel branches wave-uniformly to a templated body for both
// input decode and OUTPUT format. Pipeline: all-fp32 math, fp32 xacc via
// atomicAdd (reference segment_sum semantics), exact inline edge-MLP; only h
// staged bf16 (error ~0.05 worst-case in bf16 world, ~1e-3 in fp32 world).
// Workspace 38.4 MB.

__device__ __forceinline__ float bf2f(unsigned short s) {
    return __uint_as_float(((unsigned)s) << 16);
}
__device__ __forceinline__ unsigned short f2bf(float f) {
    unsigned u = __float_as_uint(f);
    u += 0x7fffu + ((u >> 16) & 1u);
    return (unsigned short)(u >> 16);
}
template <bool BF16>
__device__ __forceinline__ float LD(const void* p, size_t i) {
    if (BF16) return bf2f(((const unsigned short*)p)[i]);
    return ((const float*)p)[i];
}

// ---------------- dtype detection (K2-proven) ----------------
// bf16 world: u32 bits 14..7 = exponent of low bf16, concentrated in [110,135]
// for N(0,1) data (~100% hit). fp32 world: those are mantissa bits (~10% hit).
__global__ void k_detect(const unsigned* __restrict__ xw, int* __restrict__ flag) {
    __shared__ int tot;
    if (threadIdx.x == 0) tot = 0;
    __syncthreads();
    int hit = 0;
    for (int i = threadIdx.x; i < 1024; i += 256) {
        unsigned e = (xw[i] >> 7) & 0xFFu;
        if (e >= 110u && e <= 135u) hit++;
    }
    atomicAdd(&tot, hit);
    __syncthreads();
    if (threadIdx.x == 0) *flag = (tot >= 512) ? 1 : 0;
}

// ---------------- layer 0 dense: h = x_in @ W0 + b0 (bf16 staging out) --------

template <bool BF>
__device__ __forceinline__ void dense0_body(const void* __restrict__ x,
                                            const void* __restrict__ W,
                                            const void* __restrict__ b,
                                            unsigned short* __restrict__ h,
                                            float* Wl, float (*xl)[32]) {
    int t = threadIdx.x, w = t >> 6, lane = t & 63;
    for (int i = t; i < 32 * 64; i += 256) Wl[i] = LD<BF>(W, i);
    int v0 = blockIdx.x * 16 + w * 4;
    if (lane < 32) {
        #pragma unroll
        for (int n = 0; n < 4; n++)
            xl[w * 4 + n][lane] = LD<BF>(x, (size_t)(v0 + n) * 32 + lane);
    }
    __syncthreads();
    float bias = LD<BF>(b, lane);
    float a0 = bias, a1 = bias, a2 = bias, a3 = bias;
    #pragma unroll 8
    for (int k = 0; k < 32; k++) {
        float wv = Wl[k * 64 + lane];
        a0 = fmaf(xl[w * 4 + 0][k], wv, a0);
        a1 = fmaf(xl[w * 4 + 1][k], wv, a1);
        a2 = fmaf(xl[w * 4 + 2][k], wv, a2);
        a3 = fmaf(xl[w * 4 + 3][k], wv, a3);
    }
    h[(size_t)(v0 + 0) * 64 + lane] = f2bf(a0);
    h[(size_t)(v0 + 1) * 64 + lane] = f2bf(a1);
    h[(size_t)(v0 + 2) * 64 + lane] = f2bf(a2);
    h[(size_t)(v0 + 3) * 64 + lane] = f2bf(a3);
}

__global__ void k_dense0(const int* __restrict__ flag, const void* x, const void* W,
                         const void* b, unsigned short* h) {
    __shared__ float Wl[32 * 64];
    __shared__ float xl[16][32];
    if (*flag) dense0_body<true>(x, W, b, h, Wl, xl);
    else       dense0_body<false>(x, W, b, h, Wl, xl);
}

// ---------------- hidden dense: h = relu(xacc) @ W + b (bf16 staging out) -----

template <bool BF>
__device__ __forceinline__ void denseH_body(const float* __restrict__ xacc,
                                            const void* __restrict__ W, int Woff,
                                            const void* __restrict__ b, int boff,
                                            unsigned short* __restrict__ h,
                                            float* Wl, float (*xl)[64]) {
    int t = threadIdx.x, w = t >> 6, lane = t & 63;
    for (int i = t; i < 64 * 64; i += 256) Wl[i] = LD<BF>(W, Woff + i);
    int v0 = blockIdx.x * 16 + w * 4;
    #pragma unroll
    for (int n = 0; n < 4; n++)
        xl[w * 4 + n][lane] = fmaxf(xacc[(size_t)(v0 + n) * 64 + lane], 0.f);
    __syncthreads();
    float bias = LD<BF>(b, boff + lane);
    float a0 = bias, a1 = bias, a2 = bias, a3 = bias;
    #pragma unroll 8
    for (int k = 0; k < 64; k++) {
        float wv = Wl[k * 64 + lane];
        a0 = fmaf(xl[w * 4 + 0][k], wv, a0);
        a1 = fmaf(xl[w * 4 + 1][k], wv, a1);
        a2 = fmaf(xl[w * 4 + 2][k], wv, a2);
        a3 = fmaf(xl[w * 4 + 3][k], wv, a3);
    }
    h[(size_t)(v0 + 0) * 64 + lane] = f2bf(a0);
    h[(size_t)(v0 + 1) * 64 + lane] = f2bf(a1);
    h[(size_t)(v0 + 2) * 64 + lane] = f2bf(a2);
    h[(size_t)(v0 + 3) * 64 + lane] = f2bf(a3);
}

__global__ void k_denseH(const int* __restrict__ flag, const float* xacc,
                         const void* W, int Woff, const void* b, int boff,
                         unsigned short* h) {
    __shared__ float Wl[64 * 64];
    __shared__ float xl[16][64];
    if (*flag) denseH_body<true>(xacc, W, Woff, b, boff, h, Wl, xl);
    else       denseH_body<false>(xacc, W, Woff, b, boff, h, Wl, xl);
}

// ---------------- edge scatter: xacc[dst] += sigmoid(MLP(ea[e])) * h[src] -----
// one wave per edge (4/block); exact fp32 edge-MLP, wave-uniform operand loads;
// fp32 atomicAdd == reference segment_sum (mod add order). No CSR.

template <bool BF>
__device__ __forceinline__ void scat_body(const int* __restrict__ ei,
                                          const void* __restrict__ ea,
                                          const void* w1, int o1, const void* b1, int ob1,
                                          const void* w2, int o2, const void* b2, int ob2,
                                          const unsigned short* __restrict__ h,
                                          float* __restrict__ xacc) {
    int t = threadIdx.x, w = t >> 6, lane = t & 63;
    int e = blockIdx.x * 4 + w;            // grid exact: 400000*4 = 1.6M
    int src = ei[e];
    int dst = ei[N_EDGES + e];
    float a0 = LD<BF>(ea, (size_t)e * 2);
    float a1 = LD<BF>(ea, (size_t)e * 2 + 1);
    float hv = bf2f(h[(size_t)src * 64 + lane]);   // 128B coalesced gather
    float z = LD<BF>(b2, ob2);
    #pragma unroll
    for (int q = 0; q < 16; q++) {
        float hj = fmaf(a0, LD<BF>(w1, o1 + q), fmaf(a1, LD<BF>(w1, o1 + 16 + q), LD<BF>(b1, ob1 + q)));
        z = fmaf(fmaxf(hj, 0.f), LD<BF>(w2, o2 + q), z);
    }
    float ew = 1.f / (1.f + expf(-z));
    atomicAdd(&xacc[(size_t)dst * 64 + lane], ew * hv);
}

__global__ void k_edge_scatter(const int* __restrict__ flag, const int* ei, const void* ea,
                               const void* w1, int o1, const void* b1, int ob1,
                               const void* w2, int o2, const void* b2, int ob2,
                               const unsigned short* h, float* xacc) {
    if (*flag) scat_body<true>(ei, ea, w1, o1, b1, ob1, w2, o2, b2, ob2, h, xacc);
    else       scat_body<false>(ei, ea, w1, o1, b1, ob1, w2, o2, b2, ob2, h, xacc);
}

// ---------------- fused heads: 16 nodes/block; ADAPTIVE output format ---------

template <bool BF>
__device__ __forceinline__ void heads_body(const float* __restrict__ xacc,
        const void* rh1w, const void* rh1b, const void* rh2w, const void* rh2b,
        const void* meanw, const void* meanb, const void* stdw, const void* stdb,
        const void* cls1w, const void* cls1b, const void* cls2w, const void* cls2b,
        void* __restrict__ out,
        float* s_rh1, float* s_cls1, float* s_rh2, float* s_cls2,
        float* s_rh1b, float* s_cls1b, float* s_rh2b, float* s_mw, float* s_sw,
        float* s_c2b, float* s_msb,
        float (*xs)[64], float (*r1)[32], float (*c1h)[32], float (*r2)[16]) {
    int t = threadIdx.x;
    for (int i = t; i < 2048; i += 256) { s_rh1[i] = LD<BF>(rh1w, i); s_cls1[i] = LD<BF>(cls1w, i); }
    for (int i = t; i < 512; i += 256) s_rh2[i] = LD<BF>(rh2w, i);
    if (t < 64) s_cls2[t] = LD<BF>(cls2w, t);
    if (t < 32) { s_rh1b[t] = LD<BF>(rh1b, t); s_cls1b[t] = LD<BF>(cls1b, t); }
    else if (t < 48) { int i = t - 32; s_rh2b[i] = LD<BF>(rh2b, i); s_mw[i] = LD<BF>(meanw, i); s_sw[i] = LD<BF>(stdw, i); }
    else if (t == 48) { s_msb[0] = LD<BF>(meanb, 0); s_msb[1] = LD<BF>(stdb, 0); }
    else if (t == 49) { s_c2b[0] = LD<BF>(cls2b, 0); s_c2b[1] = LD<BF>(cls2b, 1); }

    int w = t >> 6, lane = t & 63;
    int v00 = blockIdx.x * 16;
    #pragma unroll
    for (int n = 0; n < 4; n++) {
        int idx = w * 4 + n;
        xs[idx][lane] = fmaxf(xacc[(size_t)(v00 + idx) * 64 + lane], 0.f);
    }
    __syncthreads();

    #pragma unroll
    for (int n = 0; n < 4; n++) {
        int idx = w * 4 + n;
        int c = lane & 31;
        const float* Wp = (lane < 32) ? s_rh1 : s_cls1;
        float acc = (lane < 32) ? s_rh1b[c] : s_cls1b[c];
        #pragma unroll 8
        for (int k = 0; k < 64; k++) acc = fmaf(xs[idx][k], Wp[k * 32 + c], acc);
        acc = fmaxf(acc, 0.f);
        if (lane < 32) r1[idx][c] = acc; else c1h[idx][c] = acc;
    }
    __syncthreads();

    #pragma unroll
    for (int n = 0; n < 4; n++) {
        int idx = w * 4 + n;
        if (lane < 16) {
            float acc = s_rh2b[lane];
            #pragma unroll
            for (int k = 0; k < 32; k++) acc = fmaf(r1[idx][k], s_rh2[k * 16 + lane], acc);
            r2[idx][lane] = fmaxf(acc, 0.f);
        }
    }
    __syncthreads();

    #pragma unroll
    for (int n = 0; n < 4; n++) {
        int idx = w * 4 + n;
        int v = v00 + idx;
        if (lane == 0) {
            float m = s_msb[0];
            #pragma unroll
            for (int k = 0; k < 16; k++) m = fmaf(r2[idx][k], s_mw[k], m);
            if (BF) ((unsigned short*)out)[v] = f2bf(m); else ((float*)out)[v] = m;
        } else if (lane == 1) {
            float sv = s_msb[1];
            #pragma unroll
            for (int k = 0; k < 16; k++) sv = fmaf(r2[idx][k], s_sw[k], sv);
            float sp = fmaxf(sv, 0.f) + log1pf(expf(-fabsf(sv)));   // stable softplus
            if (BF) ((unsigned short*)out)[N_NODES + v] = f2bf(sp); else ((float*)out)[N_NODES + v] = sp;
        } else if (lane < 4) {
            int jj = lane - 2;
            float acc = s_c2b[jj];
            #pragma unroll
            for (int k = 0; k < 32; k++) acc = fmaf(c1h[idx][k], s_cls2[k * 2 + jj], acc);
            size_t pos = (size_t)2 * N_NODES + (size_t)v * 2 + jj;
            if (BF) ((unsigned short*)out)[pos] = f2bf(acc); else ((float*)out)[pos] = acc;
        }
    }
}

__global__ void k_heads(const int* __restrict__ flag, const float* xacc,
                        const void* rh1w, const void* rh1b, const void* rh2w, const void* rh2b,
                        const void* meanw, const void* meanb, const void* stdw, const void* stdb,
                        const void* cls1w, const void* cls1b, const void* cls2w, const void* cls2b,
                        void* out) {
    __shared__ float s_rh1[64 * 32], s_cls1[64 * 32], s_rh2[32 * 16], s_cls2[32 * 2];
    __shared__ float s_rh1b[32], s_cls1b[32], s_rh2b[16], s_mw[16], s_sw[16], s_c2b[2], s_msb[2];
    __shared__ float xs[16][64], r1[16][32], c1h[16][32], r2[16][16];
    if (*flag)
        heads_body<true>(xacc, rh1w, rh1b, rh2w, rh2b, meanw, meanb, stdw, stdb,
                         cls1w, cls1b, cls2w, cls2b, out,
                         s_rh1, s_cls1, s_rh2, s_cls2, s_rh1b, s_cls1b, s_rh2b,
                         s_mw, s_sw, s_c2b, s_msb, xs, r1, c1h, r2);
    else
        heads_body<false>(xacc, rh1w, rh1b, rh2w, rh2b, meanw, meanb, stdw, stdb,
                          cls1w, cls1b, cls2w, cls2b, out,
                          s_rh1, s_cls1, s_rh2, s_cls2, s_rh1b, s_cls1b, s_rh2b,
                          s_mw, s_sw, s_c2b, s_msb, xs, r1, c1h, r2);
}

// ---------------- launch ----------------

extern "C" void kernel_launch(void* const* d_in, const int* in_sizes, int n_in,
                              void* d_out, int out_size, void* d_ws, size_t ws_size,
                              hipStream_t stream) {
    const void* x_in  = d_in[0];
    const int* ei     = (const int*)d_in[1];
    const void* ea    = d_in[2];
    const void* W0    = d_in[3];
    const void* b0    = d_in[4];
    const void* Ws    = d_in[5];
    const void* bs    = d_in[6];
    const void* ew1   = d_in[7];
    const void* eb1   = d_in[8];
    const void* ew2   = d_in[9];
    const void* eb2   = d_in[10];
    const void* rh1w  = d_in[11];
    const void* rh1b  = d_in[12];
    const void* rh2w  = d_in[13];
    const void* rh2b  = d_in[14];
    const void* meanw = d_in[15];
    const void* meanb = d_in[16];
    const void* stdw  = d_in[17];
    const void* stdb  = d_in[18];
    const void* cls1w = d_in[19];
    const void* cls1b = d_in[20];
    const void* cls2w = d_in[21];
    const void* cls2b = d_in[22];

    char* wsp = (char*)d_ws;
    auto alloc = [&](size_t bytes) -> char* {
        char* p = wsp;
        wsp += (bytes + 255) & ~(size_t)255;
        return p;
    };
    // footprint: 38.4 MB
    int* flag            = (int*)alloc(4);
    float* xacc          = (float*)alloc((size_t)N_NODES * 64 * 4);
    unsigned short* hbuf = (unsigned short*)alloc((size_t)N_NODES * 64 * 2);

    k_detect<<<1, 256, 0, stream>>>((const unsigned*)x_in, flag);

    // h0 = x_in @ W0 + b0
    k_dense0<<<6250, 256, 0, stream>>>(flag, x_in, W0, b0, hbuf);

    for (int l = 0; l < 4; l++) {
        hipMemsetAsync(xacc, 0, (size_t)N_NODES * 64 * 4, stream);
        k_edge_scatter<<<400000, 256, 0, stream>>>(flag, ei, ea,
                                                   ew1, l * 32, eb1, l * 16,
                                                   ew2, l * 16, eb2, l,
                                                   hbuf, xacc);
        if (l < 3)
            k_denseH<<<6250, 256, 0, stream>>>(flag, xacc, Ws, l * 64 * 64,
                                               bs, l * 64, hbuf);
    }
    k_heads<<<6250, 256, 0, stream>>>(flag, xacc, rh1w, rh1b, rh2w, rh2b,
                                      meanw, meanb, stdw, stdb,
                                      cls1w, cls1b, cls2w, cls2b, d_out);
}

// Round 13
// 916.445 us; speedup vs baseline: 1.9787x; 1.9787x over previous
//
#include <hip/hip_runtime.h>
#include <stdint.h>

#define N_NODES 100000
#define N_EDGES 1600000
#define NB_SCAN 391   // ceil(N_NODES/256)

// Round 13. r12 PASSED (absmax 0.0625, 1813 us) and resolved the dtype mystery:
// fp32 world (dual-world kept for safety). Profile: 4x k_edge_scatter = 1600 us,
// VALUBusy 92% (64x-redundant per-lane edge-MLP) + 409 MB/dispatch atomic HBM
// writes. Fix: CSR build + per-edge-THREAD ew precompute + atomic-free gather
// aggregation fused with dense (x fp32 in LDS) / heads. Only h staged bf16
// (same quantization as the passing r12 -> same absmax). Workspace ~53 MB.

__device__ __forceinline__ float bf2f(unsigned short s) {
    return __uint_as_float(((unsigned)s) << 16);
}
__device__ __forceinline__ unsigned short f2bf(float f) {
    unsigned u = __float_as_uint(f);
    u += 0x7fffu + ((u >> 16) & 1u);
    return (unsigned short)(u >> 16);
}
template <bool BF16>
__device__ __forceinline__ float LD(const void* p, size_t i) {
    if (BF16) return bf2f(((const unsigned short*)p)[i]);
    return ((const float*)p)[i];
}

// ---------------- dtype detection (proven r2/r12) ----------------
__global__ void k_detect(const unsigned* __restrict__ xw, int* __restrict__ flag) {
    __shared__ int tot;
    if (threadIdx.x == 0) tot = 0;
    __syncthreads();
    int hit = 0;
    for (int i = threadIdx.x; i < 1024; i += 256) {
        unsigned e = (xw[i] >> 7) & 0xFFu;
        if (e >= 110u && e <= 135u) hit++;
    }
    atomicAdd(&tot, hit);
    __syncthreads();
    if (threadIdx.x == 0) *flag = (tot >= 512) ? 1 : 0;
}

// ---------------- CSR build ----------------

__global__ void k_hist(const int* __restrict__ ei, int* __restrict__ deg) {
    int e = blockIdx.x * 256 + threadIdx.x;
    if (e < N_EDGES) atomicAdd(&deg[ei[N_EDGES + e]], 1);
}

__global__ void k_scan_partial(const int* __restrict__ deg, int* __restrict__ bsum) {
    int t = threadIdx.x;
    int i = blockIdx.x * 256 + t;
    int v = (i < N_NODES) ? deg[i] : 0;
    for (int off = 32; off > 0; off >>= 1) v += __shfl_down(v, off, 64);
    __shared__ int ws4[4];
    if ((t & 63) == 0) ws4[t >> 6] = v;
    __syncthreads();
    if (t == 0) bsum[blockIdx.x] = ws4[0] + ws4[1] + ws4[2] + ws4[3];
}

__global__ void k_scan_mid(const int* __restrict__ bsum, int* __restrict__ boff) {
    __shared__ int s[512];
    int t = threadIdx.x;
    int v = (t < NB_SCAN) ? bsum[t] : 0;
    s[t] = v;
    __syncthreads();
    for (int off = 1; off < 512; off <<= 1) {
        int x = (t >= off) ? s[t - off] : 0;
        __syncthreads();
        s[t] += x;
        __syncthreads();
    }
    if (t < NB_SCAN) boff[t] = s[t] - v;   // exclusive
}

__global__ void k_scan_final(const int* __restrict__ deg, const int* __restrict__ boff,
                             int* __restrict__ row_start, int* __restrict__ cursor) {
    __shared__ int s[256];
    int t = threadIdx.x;
    int i = blockIdx.x * 256 + t;
    int v = (i < N_NODES) ? deg[i] : 0;
    s[t] = v;
    __syncthreads();
    for (int off = 1; off < 256; off <<= 1) {
        int x = (t >= off) ? s[t - off] : 0;
        __syncthreads();
        s[t] += x;
        __syncthreads();
    }
    if (i < N_NODES) {
        int rs = boff[blockIdx.x] + s[t] - v;
        row_start[i] = rs;
        cursor[i] = rs;
    }
}

// scatter: slot per edge; store src + edge attrs (decoded to fp32, own buffer)
template <bool BF>
__device__ __forceinline__ void scatter_body(const int* __restrict__ ei, const void* __restrict__ ea,
                                             int* __restrict__ cursor, int* __restrict__ csr_src,
                                             float2* __restrict__ csr_ea) {
    int e = blockIdx.x * 256 + threadIdx.x;   // grid exact: 6250*256 = 1.6M
    int s = ei[e];
    int d = ei[N_EDGES + e];
    float a0 = LD<BF>(ea, (size_t)e * 2);
    float a1 = LD<BF>(ea, (size_t)e * 2 + 1);
    int slot = atomicAdd(&cursor[d], 1);
    csr_src[slot] = s;
    csr_ea[slot] = make_float2(a0, a1);
}

__global__ void k_scatter(const int* __restrict__ flag, const int* ei, const void* ea,
                          int* cursor, int* csr_src, float2* csr_ea) {
    if (*flag) scatter_body<true>(ei, ea, cursor, csr_src, csr_ea);
    else       scatter_body<false>(ei, ea, cursor, csr_src, csr_ea);
}

// ---------------- per-layer edge-weight MLP: ONE THREAD per edge ----------------

template <bool BF>
__device__ __forceinline__ void ew_body(const float2* __restrict__ csr_ea,
                                        const void* w1, int o1, const void* b1, int ob1,
                                        const void* w2, int o2, const void* b2, int ob2,
                                        float* __restrict__ ew_out,
                                        float* sw1, float* sb1, float* sw2, float* sb2) {
    int t = threadIdx.x;
    if (t < 32) sw1[t] = LD<BF>(w1, o1 + t);
    else if (t < 48) sb1[t - 32] = LD<BF>(b1, ob1 + t - 32);
    else if (t < 64) sw2[t - 48] = LD<BF>(w2, o2 + t - 48);
    else if (t == 64) sb2[0] = LD<BF>(b2, ob2);
    __syncthreads();
    int e = blockIdx.x * 256 + t;   // grid exact
    float2 a = csr_ea[e];
    float z = sb2[0];
    #pragma unroll
    for (int q = 0; q < 16; q++) {
        float hj = fmaf(a.x, sw1[q], fmaf(a.y, sw1[16 + q], sb1[q]));
        z = fmaf(fmaxf(hj, 0.f), sw2[q], z);
    }
    ew_out[e] = 1.f / (1.f + expf(-z));
}

__global__ void k_ew(const int* __restrict__ flag, const float2* csr_ea,
                     const void* w1, int o1, const void* b1, int ob1,
                     const void* w2, int o2, const void* b2, int ob2,
                     float* ew_out) {
    __shared__ float sw1[32], sb1[16], sw2[16], sb2[1];
    if (*flag) ew_body<true>(csr_ea, w1, o1, b1, ob1, w2, o2, b2, ob2, ew_out, sw1, sb1, sw2, sb2);
    else       ew_body<false>(csr_ea, w1, o1, b1, ob1, w2, o2, b2, ob2, ew_out, sw1, sb1, sw2, sb2);
}

// ---------------- layer 0 dense: h = x_in @ W0 + b0 (bf16 staging out) --------

template <bool BF>
__device__ __forceinline__ void dense0_body(const void* __restrict__ x,
                                            const void* __restrict__ W,
                                            const void* __restrict__ b,
                                            unsigned short* __restrict__ h,
                                            float* Wl, float (*xl)[32]) {
    int t = threadIdx.x, w = t >> 6, lane = t & 63;
    for (int i = t; i < 32 * 64; i += 256) Wl[i] = LD<BF>(W, i);
    int v0 = blockIdx.x * 16 + w * 4;
    if (lane < 32) {
        #pragma unroll
        for (int n = 0; n < 4; n++)
            xl[w * 4 + n][lane] = LD<BF>(x, (size_t)(v0 + n) * 32 + lane);
    }
    __syncthreads();
    float bias = LD<BF>(b, lane);
    float a0 = bias, a1 = bias, a2 = bias, a3 = bias;
    #pragma unroll 8
    for (int k = 0; k < 32; k++) {
        float wv = Wl[k * 64 + lane];
        a0 = fmaf(xl[w * 4 + 0][k], wv, a0);
        a1 = fmaf(xl[w * 4 + 1][k], wv, a1);
        a2 = fmaf(xl[w * 4 + 2][k], wv, a2);
        a3 = fmaf(xl[w * 4 + 3][k], wv, a3);
    }
    h[(size_t)(v0 + 0) * 64 + lane] = f2bf(a0);
    h[(size_t)(v0 + 1) * 64 + lane] = f2bf(a1);
    h[(size_t)(v0 + 2) * 64 + lane] = f2bf(a2);
    h[(size_t)(v0 + 3) * 64 + lane] = f2bf(a3);
}

__global__ void k_dense0(const int* __restrict__ flag, const void* x, const void* W,
                         const void* b, unsigned short* h) {
    __shared__ float Wl[32 * 64];
    __shared__ float xl[16][32];
    if (*flag) dense0_body<true>(x, W, b, h, Wl, xl);
    else       dense0_body<false>(x, W, b, h, Wl, xl);
}

// ---------------- aggregation core: wave per node, lane = channel -------------

__device__ __forceinline__ float agg_node(int v, const int* __restrict__ row_start,
                                          const int* __restrict__ deg,
                                          const int* __restrict__ csr_src,
                                          const float* __restrict__ ew,
                                          const unsigned short* __restrict__ h, int lane) {
    int st = row_start[v], d = deg[v];
    float acc = 0.f;
    int j = 0;
    for (; j + 1 < d; j += 2) {
        int s0 = csr_src[st + j];
        int s1 = csr_src[st + j + 1];
        float e0 = ew[st + j];
        float e1 = ew[st + j + 1];
        float h0 = bf2f(h[(size_t)s0 * 64 + lane]);
        float h1 = bf2f(h[(size_t)s1 * 64 + lane]);
        acc = fmaf(e0, h0, acc);
        acc = fmaf(e1, h1, acc);
    }
    if (j < d) {
        int s0 = csr_src[st + j];
        acc = fmaf(ew[st + j], bf2f(h[(size_t)s0 * 64 + lane]), acc);
    }
    return fmaxf(acc, 0.f);   // relu follows every aggregation (incl. final)
}

// ---------------- fused: x = relu(agg(h_in)); h_out = x @ W + b ----------------
// 4 nodes/block (4 waves); x fp32 in LDS, never stored to global

template <bool BF>
__device__ __forceinline__ void fuse_body(const int* row_start, const int* deg,
                                          const int* csr_src, const float* ew,
                                          const unsigned short* h_in,
                                          const void* W, int Woff, const void* b, int boff,
                                          unsigned short* h_out,
                                          float* Wl, float (*xs)[64]) {
    int t = threadIdx.x, w = t >> 6, lane = t & 63;
    for (int i = t; i < 64 * 64; i += 256) Wl[i] = LD<BF>(W, Woff + i);
    int v = blockIdx.x * 4 + w;
    xs[w][lane] = agg_node(v, row_start, deg, csr_src, ew, h_in, lane);
    __syncthreads();
    float acc = LD<BF>(b, boff + lane);
    #pragma unroll 8
    for (int k = 0; k < 64; k++) acc = fmaf(xs[w][k], Wl[k * 64 + lane], acc);
    h_out[(size_t)v * 64 + lane] = f2bf(acc);
}

__global__ void k_fuse(const int* __restrict__ flag,
                       const int* row_start, const int* deg, const int* csr_src,
                       const float* ew, const unsigned short* h_in,
                       const void* W, int Woff, const void* b, int boff,
                       unsigned short* h_out) {
    __shared__ float Wl[64 * 64];
    __shared__ float xs[4][64];
    if (*flag) fuse_body<true>(row_start, deg, csr_src, ew, h_in, W, Woff, b, boff, h_out, Wl, xs);
    else       fuse_body<false>(row_start, deg, csr_src, ew, h_in, W, Woff, b, boff, h_out, Wl, xs);
}

// ---------------- fused final: x3 = relu(agg(h3)); heads(x3) -> out -----------
// 4 nodes/block; x3 fp32 straight from LDS; adaptive output format

template <bool BF>
__device__ __forceinline__ void fuse_heads_body(
        const int* row_start, const int* deg, const int* csr_src,
        const float* ew, const unsigned short* h_in,
        const void* rh1w, const void* rh1b, const void* rh2w, const void* rh2b,
        const void* meanw, const void* meanb, const void* stdw, const void* stdb,
        const void* cls1w, const void* cls1b, const void* cls2w, const void* cls2b,
        void* __restrict__ out,
        float* s_rh1, float* s_cls1, float* s_rh2, float* s_cls2,
        float* s_rh1b, float* s_cls1b, float* s_rh2b, float* s_mw, float* s_sw,
        float* s_c2b, float* s_msb,
        float (*xs)[64], float (*r1)[32], float (*c1h)[32], float (*r2v)[16]) {
    int t = threadIdx.x, w = t >> 6, lane = t & 63;
    for (int i = t; i < 2048; i += 256) { s_rh1[i] = LD<BF>(rh1w, i); s_cls1[i] = LD<BF>(cls1w, i); }
    for (int i = t; i < 512; i += 256) s_rh2[i] = LD<BF>(rh2w, i);
    if (t < 64) s_cls2[t] = LD<BF>(cls2w, t);
    if (t < 32) { s_rh1b[t] = LD<BF>(rh1b, t); s_cls1b[t] = LD<BF>(cls1b, t); }
    else if (t < 48) { int i = t - 32; s_rh2b[i] = LD<BF>(rh2b, i); s_mw[i] = LD<BF>(meanw, i); s_sw[i] = LD<BF>(stdw, i); }
    else if (t == 48) { s_msb[0] = LD<BF>(meanb, 0); s_msb[1] = LD<BF>(stdb, 0); }
    else if (t == 49) { s_c2b[0] = LD<BF>(cls2b, 0); s_c2b[1] = LD<BF>(cls2b, 1); }

    int v = blockIdx.x * 4 + w;
    xs[w][lane] = agg_node(v, row_start, deg, csr_src, ew, h_in, lane);
    __syncthreads();

    {   // lanes 0-31: reg hidden1; lanes 32-63: cls hidden
        int c = lane & 31;
        const float* Wp = (lane < 32) ? s_rh1 : s_cls1;
        float acc = (lane < 32) ? s_rh1b[c] : s_cls1b[c];
        #pragma unroll 8
        for (int k = 0; k < 64; k++) acc = fmaf(xs[w][k], Wp[k * 32 + c], acc);
        acc = fmaxf(acc, 0.f);
        if (lane < 32) r1[w][c] = acc; else c1h[w][c] = acc;
    }
    __syncthreads();
    if (lane < 16) {
        float acc = s_rh2b[lane];
        #pragma unroll
        for (int k = 0; k < 32; k++) acc = fmaf(r1[w][k], s_rh2[k * 16 + lane], acc);
        r2v[w][lane] = fmaxf(acc, 0.f);
    }
    __syncthreads();
    if (lane == 0) {
        float m = s_msb[0];
        #pragma unroll
        for (int k = 0; k < 16; k++) m = fmaf(r2v[w][k], s_mw[k], m);
        if (BF) ((unsigned short*)out)[v] = f2bf(m); else ((float*)out)[v] = m;
    } else if (lane == 1) {
        float sv = s_msb[1];
        #pragma unroll
        for (int k = 0; k < 16; k++) sv = fmaf(r2v[w][k], s_sw[k], sv);
        float sp = fmaxf(sv, 0.f) + log1pf(expf(-fabsf(sv)));   // stable softplus
        if (BF) ((unsigned short*)out)[N_NODES + v] = f2bf(sp); else ((float*)out)[N_NODES + v] = sp;
    } else if (lane < 4) {
        int jj = lane - 2;
        float acc = s_c2b[jj];
        #pragma unroll
        for (int k = 0; k < 32; k++) acc = fmaf(c1h[w][k], s_cls2[k * 2 + jj], acc);
        size_t pos = (size_t)2 * N_NODES + (size_t)v * 2 + jj;
        if (BF) ((unsigned short*)out)[pos] = f2bf(acc); else ((float*)out)[pos] = acc;
    }
}

__global__ void k_fuse_heads(const int* __restrict__ flag,
                             const int* row_start, const int* deg, const int* csr_src,
                             const float* ew, const unsigned short* h_in,
                             const void* rh1w, const void* rh1b, const void* rh2w, const void* rh2b,
                             const void* meanw, const void* meanb, const void* stdw, const void* stdb,
                             const void* cls1w, const void* cls1b, const void* cls2w, const void* cls2b,
                             void* out) {
    __shared__ float s_rh1[64 * 32], s_cls1[64 * 32], s_rh2[32 * 16], s_cls2[32 * 2];
    __shared__ float s_rh1b[32], s_cls1b[32], s_rh2b[16], s_mw[16], s_sw[16], s_c2b[2], s_msb[2];
    __shared__ float xs[4][64], r1[4][32], c1h[4][32], r2v[4][16];
    if (*flag)
        fuse_heads_body<true>(row_start, deg, csr_src, ew, h_in,
                              rh1w, rh1b, rh2w, rh2b, meanw, meanb, stdw, stdb,
                              cls1w, cls1b, cls2w, cls2b, out,
                              s_rh1, s_cls1, s_rh2, s_cls2, s_rh1b, s_cls1b, s_rh2b,
                              s_mw, s_sw, s_c2b, s_msb, xs, r1, c1h, r2v);
    else
        fuse_heads_body<false>(row_start, deg, csr_src, ew, h_in,
                               rh1w, rh1b, rh2w, rh2b, meanw, meanb, stdw, stdb,
                               cls1w, cls1b, cls2w, cls2b, out,
                               s_rh1, s_cls1, s_rh2, s_cls2, s_rh1b, s_cls1b, s_rh2b,
                               s_mw, s_sw, s_c2b, s_msb, xs, r1, c1h, r2v);
}

// ---------------- launch ----------------

extern "C" void kernel_launch(void* const* d_in, const int* in_sizes, int n_in,
                              void* d_out, int out_size, void* d_ws, size_t ws_size,
                              hipStream_t stream) {
    const void* x_in  = d_in[0];
    const int* ei     = (const int*)d_in[1];
    const void* ea    = d_in[2];
    const void* W0    = d_in[3];
    const void* b0    = d_in[4];
    const void* Ws    = d_in[5];
    const void* bs    = d_in[6];
    const void* ew1   = d_in[7];
    const void* eb1   = d_in[8];
    const void* ew2   = d_in[9];
    const void* eb2   = d_in[10];
    const void* rh1w  = d_in[11];
    const void* rh1b  = d_in[12];
    const void* rh2w  = d_in[13];
    const void* rh2b  = d_in[14];
    const void* meanw = d_in[15];
    const void* meanb = d_in[16];
    const void* stdw  = d_in[17];
    const void* stdb  = d_in[18];
    const void* cls1w = d_in[19];
    const void* cls1b = d_in[20];
    const void* cls2w = d_in[21];
    const void* cls2b = d_in[22];

    char* wsp = (char*)d_ws;
    auto alloc = [&](size_t bytes) -> char* {
        char* p = wsp;
        wsp += (bytes + 255) & ~(size_t)255;
        return p;
    };
    // footprint ~52.7 MB
    int* flag       = (int*)alloc(4);
    int* deg        = (int*)alloc((size_t)N_NODES * 4);
    int* row_start  = (int*)alloc((size_t)N_NODES * 4);
    int* cursor     = (int*)alloc((size_t)N_NODES * 4);
    int* bsum       = (int*)alloc((size_t)NB_SCAN * 4);
    int* boff       = (int*)alloc((size_t)NB_SCAN * 4);
    int* csr_src    = (int*)alloc((size_t)N_EDGES * 4);
    float2* csr_ea  = (float2*)alloc((size_t)N_EDGES * 8);
    float* ew_buf   = (float*)alloc((size_t)N_EDGES * 4);
    unsigned short* hA = (unsigned short*)alloc((size_t)N_NODES * 64 * 2);
    unsigned short* hB = (unsigned short*)alloc((size_t)N_NODES * 64 * 2);

    k_detect<<<1, 256, 0, stream>>>((const unsigned*)x_in, flag);
    hipMemsetAsync(deg, 0, (size_t)N_NODES * 4, stream);
    k_hist<<<6250, 256, 0, stream>>>(ei, deg);
    k_scan_partial<<<NB_SCAN, 256, 0, stream>>>(deg, bsum);
    k_scan_mid<<<1, 512, 0, stream>>>(bsum, boff);
    k_scan_final<<<NB_SCAN, 256, 0, stream>>>(deg, boff, row_start, cursor);
    k_scatter<<<6250, 256, 0, stream>>>(flag, ei, ea, cursor, csr_src, csr_ea);

    // h0 = x_in @ W0 + b0
    k_dense0<<<6250, 256, 0, stream>>>(flag, x_in, W0, b0, hA);

    unsigned short* hin = hA;
    unsigned short* hout = hB;
    for (int l = 0; l < 3; l++) {
        k_ew<<<6250, 256, 0, stream>>>(flag, csr_ea, ew1, l * 32, eb1, l * 16,
                                       ew2, l * 16, eb2, l, ew_buf);
        k_fuse<<<25000, 256, 0, stream>>>(flag, row_start, deg, csr_src, ew_buf, hin,
                                          Ws, l * 64 * 64, bs, l * 64, hout);
        unsigned short* tmp = hin; hin = hout; hout = tmp;
    }
    k_ew<<<6250, 256, 0, stream>>>(flag, csr_ea, ew1, 3 * 32, eb1, 3 * 16,
                                   ew2, 3 * 16, eb2, 3, ew_buf);
    k_fuse_heads<<<25000, 256, 0, stream>>>(flag, row_start, deg, csr_src, ew_buf, hin,
                                            rh1w, rh1b, rh2w, rh2b, meanw, meanb,
                                            stdw, stdb, cls1w, cls1b, cls2w, cls2b,
                                            d_out);
}

// Round 14
// 711.743 us; speedup vs baseline: 2.5477x; 1.2876x over previous
//
#include <hip/hip_runtime.h>
#include <stdint.h>

#define N_NODES 100000
#define N_EDGES 1600000
#define NB_SCAN 391   // ceil(N_NODES/256)

// Round 14. r13: 916 us, agg kernels (4 x ~180 us) latency-bound on the serial
// csr_src->gather dependent chain (VALUBusy 48%, HBM 6%). Fix: lane-parallel
// index/ew preload + __shfl broadcast (index load off the critical path),
// 4-way unrolled independent gathers, 8 nodes/block k_fuse (W-staging amortized,
// deg-variance averaged), 16 nodes/block k_fuse_heads. Edge order per node
// unchanged -> absmax stays 0.0625.

__device__ __forceinline__ float bf2f(unsigned short s) {
    return __uint_as_float(((unsigned)s) << 16);
}
__device__ __forceinline__ unsigned short f2bf(float f) {
    unsigned u = __float_as_uint(f);
    u += 0x7fffu + ((u >> 16) & 1u);
    return (unsigned short)(u >> 16);
}
template <bool BF16>
__device__ __forceinline__ float LD(const void* p, size_t i) {
    if (BF16) return bf2f(((const unsigned short*)p)[i]);
    return ((const float*)p)[i];
}

// ---------------- dtype detection (proven) ----------------
__global__ void k_detect(const unsigned* __restrict__ xw, int* __restrict__ flag) {
    __shared__ int tot;
    if (threadIdx.x == 0) tot = 0;
    __syncthreads();
    int hit = 0;
    for (int i = threadIdx.x; i < 1024; i += 256) {
        unsigned e = (xw[i] >> 7) & 0xFFu;
        if (e >= 110u && e <= 135u) hit++;
    }
    atomicAdd(&tot, hit);
    __syncthreads();
    if (threadIdx.x == 0) *flag = (tot >= 512) ? 1 : 0;
}

// ---------------- CSR build ----------------

__global__ void k_hist(const int* __restrict__ ei, int* __restrict__ deg) {
    int e = blockIdx.x * 256 + threadIdx.x;
    if (e < N_EDGES) atomicAdd(&deg[ei[N_EDGES + e]], 1);
}

__global__ void k_scan_partial(const int* __restrict__ deg, int* __restrict__ bsum) {
    int t = threadIdx.x;
    int i = blockIdx.x * 256 + t;
    int v = (i < N_NODES) ? deg[i] : 0;
    for (int off = 32; off > 0; off >>= 1) v += __shfl_down(v, off, 64);
    __shared__ int ws4[4];
    if ((t & 63) == 0) ws4[t >> 6] = v;
    __syncthreads();
    if (t == 0) bsum[blockIdx.x] = ws4[0] + ws4[1] + ws4[2] + ws4[3];
}

__global__ void k_scan_mid(const int* __restrict__ bsum, int* __restrict__ boff) {
    __shared__ int s[512];
    int t = threadIdx.x;
    int v = (t < NB_SCAN) ? bsum[t] : 0;
    s[t] = v;
    __syncthreads();
    for (int off = 1; off < 512; off <<= 1) {
        int x = (t >= off) ? s[t - off] : 0;
        __syncthreads();
        s[t] += x;
        __syncthreads();
    }
    if (t < NB_SCAN) boff[t] = s[t] - v;   // exclusive
}

__global__ void k_scan_final(const int* __restrict__ deg, const int* __restrict__ boff,
                             int* __restrict__ row_start, int* __restrict__ cursor) {
    __shared__ int s[256];
    int t = threadIdx.x;
    int i = blockIdx.x * 256 + t;
    int v = (i < N_NODES) ? deg[i] : 0;
    s[t] = v;
    __syncthreads();
    for (int off = 1; off < 256; off <<= 1) {
        int x = (t >= off) ? s[t - off] : 0;
        __syncthreads();
        s[t] += x;
        __syncthreads();
    }
    if (i < N_NODES) {
        int rs = boff[blockIdx.x] + s[t] - v;
        row_start[i] = rs;
        cursor[i] = rs;
    }
}

template <bool BF>
__device__ __forceinline__ void scatter_body(const int* __restrict__ ei, const void* __restrict__ ea,
                                             int* __restrict__ cursor, int* __restrict__ csr_src,
                                             float2* __restrict__ csr_ea) {
    int e = blockIdx.x * 256 + threadIdx.x;   // grid exact: 6250*256 = 1.6M
    int s = ei[e];
    int d = ei[N_EDGES + e];
    float a0 = LD<BF>(ea, (size_t)e * 2);
    float a1 = LD<BF>(ea, (size_t)e * 2 + 1);
    int slot = atomicAdd(&cursor[d], 1);
    csr_src[slot] = s;
    csr_ea[slot] = make_float2(a0, a1);
}

__global__ void k_scatter(const int* __restrict__ flag, const int* ei, const void* ea,
                          int* cursor, int* csr_src, float2* csr_ea) {
    if (*flag) scatter_body<true>(ei, ea, cursor, csr_src, csr_ea);
    else       scatter_body<false>(ei, ea, cursor, csr_src, csr_ea);
}

// ---------------- per-layer edge-weight MLP: one thread per edge ----------------

template <bool BF>
__device__ __forceinline__ void ew_body(const float2* __restrict__ csr_ea,
                                        const void* w1, int o1, const void* b1, int ob1,
                                        const void* w2, int o2, const void* b2, int ob2,
                                        float* __restrict__ ew_out,
                                        float* sw1, float* sb1, float* sw2, float* sb2) {
    int t = threadIdx.x;
    if (t < 32) sw1[t] = LD<BF>(w1, o1 + t);
    else if (t < 48) sb1[t - 32] = LD<BF>(b1, ob1 + t - 32);
    else if (t < 64) sw2[t - 48] = LD<BF>(w2, o2 + t - 48);
    else if (t == 64) sb2[0] = LD<BF>(b2, ob2);
    __syncthreads();
    int e = blockIdx.x * 256 + t;   // grid exact
    float2 a = csr_ea[e];
    float z = sb2[0];
    #pragma unroll
    for (int q = 0; q < 16; q++) {
        float hj = fmaf(a.x, sw1[q], fmaf(a.y, sw1[16 + q], sb1[q]));
        z = fmaf(fmaxf(hj, 0.f), sw2[q], z);
    }
    ew_out[e] = 1.f / (1.f + expf(-z));
}

__global__ void k_ew(const int* __restrict__ flag, const float2* csr_ea,
                     const void* w1, int o1, const void* b1, int ob1,
                     const void* w2, int o2, const void* b2, int ob2,
                     float* ew_out) {
    __shared__ float sw1[32], sb1[16], sw2[16], sb2[1];
    if (*flag) ew_body<true>(csr_ea, w1, o1, b1, ob1, w2, o2, b2, ob2, ew_out, sw1, sb1, sw2, sb2);
    else       ew_body<false>(csr_ea, w1, o1, b1, ob1, w2, o2, b2, ob2, ew_out, sw1, sb1, sw2, sb2);
}

// ---------------- layer 0 dense ----------------

template <bool BF>
__device__ __forceinline__ void dense0_body(const void* __restrict__ x,
                                            const void* __restrict__ W,
                                            const void* __restrict__ b,
                                            unsigned short* __restrict__ h,
                                            float* Wl, float (*xl)[32]) {
    int t = threadIdx.x, w = t >> 6, lane = t & 63;
    for (int i = t; i < 32 * 64; i += 256) Wl[i] = LD<BF>(W, i);
    int v0 = blockIdx.x * 16 + w * 4;
    if (lane < 32) {
        #pragma unroll
        for (int n = 0; n < 4; n++)
            xl[w * 4 + n][lane] = LD<BF>(x, (size_t)(v0 + n) * 32 + lane);
    }
    __syncthreads();
    float bias = LD<BF>(b, lane);
    float a0 = bias, a1 = bias, a2 = bias, a3 = bias;
    #pragma unroll 8
    for (int k = 0; k < 32; k++) {
        float wv = Wl[k * 64 + lane];
        a0 = fmaf(xl[w * 4 + 0][k], wv, a0);
        a1 = fmaf(xl[w * 4 + 1][k], wv, a1);
        a2 = fmaf(xl[w * 4 + 2][k], wv, a2);
        a3 = fmaf(xl[w * 4 + 3][k], wv, a3);
    }
    h[(size_t)(v0 + 0) * 64 + lane] = f2bf(a0);
    h[(size_t)(v0 + 1) * 64 + lane] = f2bf(a1);
    h[(size_t)(v0 + 2) * 64 + lane] = f2bf(a2);
    h[(size_t)(v0 + 3) * 64 + lane] = f2bf(a3);
}

__global__ void k_dense0(const int* __restrict__ flag, const void* x, const void* W,
                         const void* b, unsigned short* h) {
    __shared__ float Wl[32 * 64];
    __shared__ float xl[16][32];
    if (*flag) dense0_body<true>(x, W, b, h, Wl, xl);
    else       dense0_body<false>(x, W, b, h, Wl, xl);
}

// ---------------- aggregation: lane-preloaded indices + shfl broadcast --------
// lane j preloads csr_src/ew for edge j (one coalesced load per 64 edges);
// per edge only the h-row gather is on the critical path; 4 gathers in flight.
// Edge order (ascending j) identical to r13 -> same numerics.

__device__ __forceinline__ float agg_node_shfl(int st, int d,
                                               const int* __restrict__ csr_src,
                                               const float* __restrict__ ew,
                                               const unsigned short* __restrict__ h,
                                               int lane) {
    float acc = 0.f;
    for (int base = 0; base < d; base += 64) {
        int cnt = min(64, d - base);
        int idx = 0;
        float ev = 0.f;
        if (lane < cnt) {
            idx = csr_src[st + base + lane];
            ev = ew[st + base + lane];
        }
        int j = 0;
        for (; j + 3 < cnt; j += 4) {
            int s0 = __shfl(idx, j, 64);
            int s1 = __shfl(idx, j + 1, 64);
            int s2 = __shfl(idx, j + 2, 64);
            int s3 = __shfl(idx, j + 3, 64);
            float e0 = __shfl(ev, j, 64);
            float e1 = __shfl(ev, j + 1, 64);
            float e2 = __shfl(ev, j + 2, 64);
            float e3 = __shfl(ev, j + 3, 64);
            float h0 = bf2f(h[(size_t)s0 * 64 + lane]);
            float h1 = bf2f(h[(size_t)s1 * 64 + lane]);
            float h2 = bf2f(h[(size_t)s2 * 64 + lane]);
            float h3 = bf2f(h[(size_t)s3 * 64 + lane]);
            acc = fmaf(e0, h0, acc);
            acc = fmaf(e1, h1, acc);
            acc = fmaf(e2, h2, acc);
            acc = fmaf(e3, h3, acc);
        }
        for (; j < cnt; j++) {
            int s0 = __shfl(idx, j, 64);
            float e0 = __shfl(ev, j, 64);
            acc = fmaf(e0, bf2f(h[(size_t)s0 * 64 + lane]), acc);
        }
    }
    return fmaxf(acc, 0.f);   // relu follows every aggregation (incl. final)
}

// ---------------- fused: x = relu(agg(h_in)); h_out = x @ W + b ----------------
// 8 nodes/block (4 waves x 2 nodes): W-staging amortized, deg variance averaged

template <bool BF>
__device__ __forceinline__ void fuse_body(const int* row_start, const int* deg,
                                          const int* csr_src, const float* ew,
                                          const unsigned short* h_in,
                                          const void* W, int Woff, const void* b, int boff,
                                          unsigned short* h_out,
                                          float* Wl, float (*xs)[64]) {
    int t = threadIdx.x, w = t >> 6, lane = t & 63;
    for (int i = t; i < 64 * 64; i += 256) Wl[i] = LD<BF>(W, Woff + i);
    int v0 = blockIdx.x * 8 + w * 2;
    #pragma unroll
    for (int n = 0; n < 2; n++) {
        int v = v0 + n;
        xs[w * 2 + n][lane] = agg_node_shfl(row_start[v], deg[v], csr_src, ew, h_in, lane);
    }
    __syncthreads();
    float bias = LD<BF>(b, boff + lane);
    float a0 = bias, a1 = bias;
    #pragma unroll 8
    for (int k = 0; k < 64; k++) {
        float wv = Wl[k * 64 + lane];
        a0 = fmaf(xs[w * 2 + 0][k], wv, a0);
        a1 = fmaf(xs[w * 2 + 1][k], wv, a1);
    }
    h_out[(size_t)(v0 + 0) * 64 + lane] = f2bf(a0);
    h_out[(size_t)(v0 + 1) * 64 + lane] = f2bf(a1);
}

__global__ void k_fuse(const int* __restrict__ flag,
                       const int* row_start, const int* deg, const int* csr_src,
                       const float* ew, const unsigned short* h_in,
                       const void* W, int Woff, const void* b, int boff,
                       unsigned short* h_out) {
    __shared__ float Wl[64 * 64];
    __shared__ float xs[8][64];
    if (*flag) fuse_body<true>(row_start, deg, csr_src, ew, h_in, W, Woff, b, boff, h_out, Wl, xs);
    else       fuse_body<false>(row_start, deg, csr_src, ew, h_in, W, Woff, b, boff, h_out, Wl, xs);
}

// ---------------- fused final: x3 = relu(agg(h3)); heads -> out ---------------
// 16 nodes/block (4 waves x 4 nodes): head-weight staging amortized 4x

template <bool BF>
__device__ __forceinline__ void fuse_heads_body(
        const int* row_start, const int* deg, const int* csr_src,
        const float* ew, const unsigned short* h_in,
        const void* rh1w, const void* rh1b, const void* rh2w, const void* rh2b,
        const void* meanw, const void* meanb, const void* stdw, const void* stdb,
        const void* cls1w, const void* cls1b, const void* cls2w, const void* cls2b,
        void* __restrict__ out,
        float* s_rh1, float* s_cls1, float* s_rh2, float* s_cls2,
        float* s_rh1b, float* s_cls1b, float* s_rh2b, float* s_mw, float* s_sw,
        float* s_c2b, float* s_msb,
        float (*xs)[64], float (*r1)[32], float (*c1h)[32], float (*r2)[16]) {
    int t = threadIdx.x, w = t >> 6, lane = t & 63;
    for (int i = t; i < 2048; i += 256) { s_rh1[i] = LD<BF>(rh1w, i); s_cls1[i] = LD<BF>(cls1w, i); }
    for (int i = t; i < 512; i += 256) s_rh2[i] = LD<BF>(rh2w, i);
    if (t < 64) s_cls2[t] = LD<BF>(cls2w, t);
    if (t < 32) { s_rh1b[t] = LD<BF>(rh1b, t); s_cls1b[t] = LD<BF>(cls1b, t); }
    else if (t < 48) { int i = t - 32; s_rh2b[i] = LD<BF>(rh2b, i); s_mw[i] = LD<BF>(meanw, i); s_sw[i] = LD<BF>(stdw, i); }
    else if (t == 48) { s_msb[0] = LD<BF>(meanb, 0); s_msb[1] = LD<BF>(stdb, 0); }
    else if (t == 49) { s_c2b[0] = LD<BF>(cls2b, 0); s_c2b[1] = LD<BF>(cls2b, 1); }

    int v00 = blockIdx.x * 16;
    #pragma unroll
    for (int n = 0; n < 4; n++) {
        int idx = w * 4 + n;
        int v = v00 + idx;
        xs[idx][lane] = agg_node_shfl(row_start[v], deg[v], csr_src, ew, h_in, lane);
    }
    __syncthreads();

    #pragma unroll
    for (int n = 0; n < 4; n++) {
        int idx = w * 4 + n;
        int c = lane & 31;
        const float* Wp = (lane < 32) ? s_rh1 : s_cls1;
        float acc = (lane < 32) ? s_rh1b[c] : s_cls1b[c];
        #pragma unroll 8
        for (int k = 0; k < 64; k++) acc = fmaf(xs[idx][k], Wp[k * 32 + c], acc);
        acc = fmaxf(acc, 0.f);
        if (lane < 32) r1[idx][c] = acc; else c1h[idx][c] = acc;
    }
    __syncthreads();

    #pragma unroll
    for (int n = 0; n < 4; n++) {
        int idx = w * 4 + n;
        if (lane < 16) {
            float acc = s_rh2b[lane];
            #pragma unroll
            for (int k = 0; k < 32; k++) acc = fmaf(r1[idx][k], s_rh2[k * 16 + lane], acc);
            r2[idx][lane] = fmaxf(acc, 0.f);
        }
    }
    __syncthreads();

    #pragma unroll
    for (int n = 0; n < 4; n++) {
        int idx = w * 4 + n;
        int v = v00 + idx;
        if (lane == 0) {
            float m = s_msb[0];
            #pragma unroll
            for (int k = 0; k < 16; k++) m = fmaf(r2[idx][k], s_mw[k], m);
            if (BF) ((unsigned short*)out)[v] = f2bf(m); else ((float*)out)[v] = m;
        } else if (lane == 1) {
            float sv = s_msb[1];
            #pragma unroll
            for (int k = 0; k < 16; k++) sv = fmaf(r2[idx][k], s_sw[k], sv);
            float sp = fmaxf(sv, 0.f) + log1pf(expf(-fabsf(sv)));   // stable softplus
            if (BF) ((unsigned short*)out)[N_NODES + v] = f2bf(sp); else ((float*)out)[N_NODES + v] = sp;
        } else if (lane < 4) {
            int jj = lane - 2;
            float acc = s_c2b[jj];
            #pragma unroll
            for (int k = 0; k < 32; k++) acc = fmaf(c1h[idx][k], s_cls2[k * 2 + jj], acc);
            size_t pos = (size_t)2 * N_NODES + (size_t)v * 2 + jj;
            if (BF) ((unsigned short*)out)[pos] = f2bf(acc); else ((float*)out)[pos] = acc;
        }
    }
}

__global__ void k_fuse_heads(const int* __restrict__ flag,
                             const int* row_start, const int* deg, const int* csr_src,
                             const float* ew, const unsigned short* h_in,
                             const void* rh1w, const void* rh1b, const void* rh2w, const void* rh2b,
                             const void* meanw, const void* meanb, const void* stdw, const void* stdb,
                             const void* cls1w, const void* cls1b, const void* cls2w, const void* cls2b,
                             void* out) {
    __shared__ float s_rh1[64 * 32], s_cls1[64 * 32], s_rh2[32 * 16], s_cls2[32 * 2];
    __shared__ float s_rh1b[32], s_cls1b[32], s_rh2b[16], s_mw[16], s_sw[16], s_c2b[2], s_msb[2];
    __shared__ float xs[16][64], r1[16][32], c1h[16][32], r2[16][16];
    if (*flag)
        fuse_heads_body<true>(row_start, deg, csr_src, ew, h_in,
                              rh1w, rh1b, rh2w, rh2b, meanw, meanb, stdw, stdb,
                              cls1w, cls1b, cls2w, cls2b, out,
                              s_rh1, s_cls1, s_rh2, s_cls2, s_rh1b, s_cls1b, s_rh2b,
                              s_mw, s_sw, s_c2b, s_msb, xs, r1, c1h, r2);
    else
        fuse_heads_body<false>(row_start, deg, csr_src, ew, h_in,
                               rh1w, rh1b, rh2w, rh2b, meanw, meanb, stdw, stdb,
                               cls1w, cls1b, cls2w, cls2b, out,
                               s_rh1, s_cls1, s_rh2, s_cls2, s_rh1b, s_cls1b, s_rh2b,
                               s_mw, s_sw, s_c2b, s_msb, xs, r1, c1h, r2);
}

// ---------------- launch ----------------

extern "C" void kernel_launch(void* const* d_in, const int* in_sizes, int n_in,
                              void* d_out, int out_size, void* d_ws, size_t ws_size,
                              hipStream_t stream) {
    const void* x_in  = d_in[0];
    const int* ei     = (const int*)d_in[1];
    const void* ea    = d_in[2];
    const void* W0    = d_in[3];
    const void* b0    = d_in[4];
    const void* Ws    = d_in[5];
    const void* bs    = d_in[6];
    const void* ew1   = d_in[7];
    const void* eb1   = d_in[8];
    const void* ew2   = d_in[9];
    const void* eb2   = d_in[10];
    const void* rh1w  = d_in[11];
    const void* rh1b  = d_in[12];
    const void* rh2w  = d_in[13];
    const void* rh2b  = d_in[14];
    const void* meanw = d_in[15];
    const void* meanb = d_in[16];
    const void* stdw  = d_in[17];
    const void* stdb  = d_in[18];
    const void* cls1w = d_in[19];
    const void* cls1b = d_in[20];
    const void* cls2w = d_in[21];
    const void* cls2b = d_in[22];

    char* wsp = (char*)d_ws;
    auto alloc = [&](size_t bytes) -> char* {
        char* p = wsp;
        wsp += (bytes + 255) & ~(size_t)255;
        return p;
    };
    // footprint ~52.7 MB
    int* flag       = (int*)alloc(4);
    int* deg        = (int*)alloc((size_t)N_NODES * 4);
    int* row_start  = (int*)alloc((size_t)N_NODES * 4);
    int* cursor     = (int*)alloc((size_t)N_NODES * 4);
    int* bsum       = (int*)alloc((size_t)NB_SCAN * 4);
    int* boff       = (int*)alloc((size_t)NB_SCAN * 4);
    int* csr_src    = (int*)alloc((size_t)N_EDGES * 4);
    float2* csr_ea  = (float2*)alloc((size_t)N_EDGES * 8);
    float* ew_buf   = (float*)alloc((size_t)N_EDGES * 4);
    unsigned short* hA = (unsigned short*)alloc((size_t)N_NODES * 64 * 2);
    unsigned short* hB = (unsigned short*)alloc((size_t)N_NODES * 64 * 2);

    k_detect<<<1, 256, 0, stream>>>((const unsigned*)x_in, flag);
    hipMemsetAsync(deg, 0, (size_t)N_NODES * 4, stream);
    k_hist<<<6250, 256, 0, stream>>>(ei, deg);
    k_scan_partial<<<NB_SCAN, 256, 0, stream>>>(deg, bsum);
    k_scan_mid<<<1, 512, 0, stream>>>(bsum, boff);
    k_scan_final<<<NB_SCAN, 256, 0, stream>>>(deg, boff, row_start, cursor);
    k_scatter<<<6250, 256, 0, stream>>>(flag, ei, ea, cursor, csr_src, csr_ea);

    // h0 = x_in @ W0 + b0
    k_dense0<<<6250, 256, 0, stream>>>(flag, x_in, W0, b0, hA);

    unsigned short* hin = hA;
    unsigned short* hout = hB;
    for (int l = 0; l < 3; l++) {
        k_ew<<<6250, 256, 0, stream>>>(flag, csr_ea, ew1, l * 32, eb1, l * 16,
                                       ew2, l * 16, eb2, l, ew_buf);
        k_fuse<<<12500, 256, 0, stream>>>(flag, row_start, deg, csr_src, ew_buf, hin,
                                          Ws, l * 64 * 64, bs, l * 64, hout);
        unsigned short* tmp = hin; hin = hout; hout = tmp;
    }
    k_ew<<<6250, 256, 0, stream>>>(flag, csr_ea, ew1, 3 * 32, eb1, 3 * 16,
                                   ew2, 3 * 16, eb2, 3, ew_buf);
    k_fuse_heads<<<6250, 256, 0, stream>>>(flag, row_start, deg, csr_src, ew_buf, hin,
                                           rh1w, rh1b, rh2w, rh2b, meanw, meanb,
                                           stdw, stdb, cls1w, cls1b, cls2w, cls2b,
                                           d_out);
}

// Round 15
// 645.430 us; speedup vs baseline: 2.8095x; 1.1027x over previous
//
#include <hip/hip_runtime.h>
#include <stdint.h>

#define N_NODES 100000
#define N_EDGES 1600000
#define NB_SCAN 391   // ceil(N_NODES/256)

// Round 15. r14: 712 us. Agg kernels still gather-latency-bound (VALUBusy 53%,
// FETCH 82 MB = h-table replicated over 8 XCD L2s; 2B/lane ushort gathers).
// Changes: (1) dual-edge u32 gathers — lane halves take even/odd edges, each
// lane carries 2 channels; one inst fetches 2 edges (256B/wave), halving
// gather instructions; __shfl_xor(32) merges halves. (2) 4-layer edge-MLP
// folded into k_scatter (one thread/edge, fp32 ew4 buffer) — removes 4 k_ew
// dispatches. Numerics: only fp32 add order changes -> absmax stays 0.0625.
// ws 65.6 MB (< 78.2 proven).

__device__ __forceinline__ float bf2f(unsigned short s) {
    return __uint_as_float(((unsigned)s) << 16);
}
__device__ __forceinline__ unsigned short f2bf(float f) {
    unsigned u = __float_as_uint(f);
    u += 0x7fffu + ((u >> 16) & 1u);
    return (unsigned short)(u >> 16);
}
template <bool BF16>
__device__ __forceinline__ float LD(const void* p, size_t i) {
    if (BF16) return bf2f(((const unsigned short*)p)[i]);
    return ((const float*)p)[i];
}

// ---------------- dtype detection (proven) ----------------
__global__ void k_detect(const unsigned* __restrict__ xw, int* __restrict__ flag) {
    __shared__ int tot;
    if (threadIdx.x == 0) tot = 0;
    __syncthreads();
    int hit = 0;
    for (int i = threadIdx.x; i < 1024; i += 256) {
        unsigned e = (xw[i] >> 7) & 0xFFu;
        if (e >= 110u && e <= 135u) hit++;
    }
    atomicAdd(&tot, hit);
    __syncthreads();
    if (threadIdx.x == 0) *flag = (tot >= 512) ? 1 : 0;
}

// ---------------- CSR build ----------------

__global__ void k_hist(const int* __restrict__ ei, int* __restrict__ deg) {
    int e = blockIdx.x * 256 + threadIdx.x;
    if (e < N_EDGES) atomicAdd(&deg[ei[N_EDGES + e]], 1);
}

__global__ void k_scan_partial(const int* __restrict__ deg, int* __restrict__ bsum) {
    int t = threadIdx.x;
    int i = blockIdx.x * 256 + t;
    int v = (i < N_NODES) ? deg[i] : 0;
    for (int off = 32; off > 0; off >>= 1) v += __shfl_down(v, off, 64);
    __shared__ int ws4[4];
    if ((t & 63) == 0) ws4[t >> 6] = v;
    __syncthreads();
    if (t == 0) bsum[blockIdx.x] = ws4[0] + ws4[1] + ws4[2] + ws4[3];
}

__global__ void k_scan_mid(const int* __restrict__ bsum, int* __restrict__ boff) {
    __shared__ int s[512];
    int t = threadIdx.x;
    int v = (t < NB_SCAN) ? bsum[t] : 0;
    s[t] = v;
    __syncthreads();
    for (int off = 1; off < 512; off <<= 1) {
        int x = (t >= off) ? s[t - off] : 0;
        __syncthreads();
        s[t] += x;
        __syncthreads();
    }
    if (t < NB_SCAN) boff[t] = s[t] - v;   // exclusive
}

__global__ void k_scan_final(const int* __restrict__ deg, const int* __restrict__ boff,
                             int* __restrict__ row_start, int* __restrict__ cursor) {
    __shared__ int s[256];
    int t = threadIdx.x;
    int i = blockIdx.x * 256 + t;
    int v = (i < N_NODES) ? deg[i] : 0;
    s[t] = v;
    __syncthreads();
    for (int off = 1; off < 256; off <<= 1) {
        int x = (t >= off) ? s[t - off] : 0;
        __syncthreads();
        s[t] += x;
        __syncthreads();
    }
    if (i < N_NODES) {
        int rs = boff[blockIdx.x] + s[t] - v;
        row_start[i] = rs;
        cursor[i] = rs;
    }
}

// ---------------- CSR scatter + 4-layer edge-weight MLP (one thread/edge) -----

template <bool BF>
__device__ __forceinline__ void scatter_ew_body(
        const int* __restrict__ ei, const void* __restrict__ ea,
        const void* ew1, const void* eb1, const void* ew2, const void* eb2,
        int* __restrict__ cursor, int* __restrict__ csr_src,
        float* __restrict__ ew4,
        float (*w1)[2][16], float (*b1)[16], float (*w2)[16], float* b2) {
    int t = threadIdx.x;
    if (t < 128) ((float*)w1)[t] = LD<BF>(ew1, t);
    else if (t < 192) ((float*)b1)[t - 128] = LD<BF>(eb1, t - 128);
    else ((float*)w2)[t - 192] = LD<BF>(ew2, t - 192);
    if (t < 4) b2[t] = LD<BF>(eb2, t);
    __syncthreads();

    int e = blockIdx.x * 256 + t;   // grid exact: 6250*256 = 1.6M
    int s = ei[e];
    int d = ei[N_EDGES + e];
    float a0 = LD<BF>(ea, (size_t)e * 2);
    float a1 = LD<BF>(ea, (size_t)e * 2 + 1);
    int slot = atomicAdd(&cursor[d], 1);
    csr_src[slot] = s;
    #pragma unroll
    for (int l = 0; l < 4; l++) {
        float z = b2[l];
        #pragma unroll
        for (int q = 0; q < 16; q++) {
            float hj = fmaf(a0, w1[l][0][q], fmaf(a1, w1[l][1][q], b1[l][q]));
            z = fmaf(fmaxf(hj, 0.f), w2[l][q], z);
        }
        ew4[(size_t)l * N_EDGES + slot] = 1.f / (1.f + expf(-z));
    }
}

__global__ void k_scatter_ew(const int* __restrict__ flag, const int* ei, const void* ea,
                             const void* ew1, const void* eb1, const void* ew2, const void* eb2,
                             int* cursor, int* csr_src, float* ew4) {
    __shared__ float w1[4][2][16], b1[4][16], w2[4][16], b2[4];
    if (*flag) scatter_ew_body<true>(ei, ea, ew1, eb1, ew2, eb2, cursor, csr_src, ew4, w1, b1, w2, b2);
    else       scatter_ew_body<false>(ei, ea, ew1, eb1, ew2, eb2, cursor, csr_src, ew4, w1, b1, w2, b2);
}

// ---------------- layer 0 dense ----------------

template <bool BF>
__device__ __forceinline__ void dense0_body(const void* __restrict__ x,
                                            const void* __restrict__ W,
                                            const void* __restrict__ b,
                                            unsigned short* __restrict__ h,
                                            float* Wl, float (*xl)[32]) {
    int t = threadIdx.x, w = t >> 6, lane = t & 63;
    for (int i = t; i < 32 * 64; i += 256) Wl[i] = LD<BF>(W, i);
    int v0 = blockIdx.x * 16 + w * 4;
    if (lane < 32) {
        #pragma unroll
        for (int n = 0; n < 4; n++)
            xl[w * 4 + n][lane] = LD<BF>(x, (size_t)(v0 + n) * 32 + lane);
    }
    __syncthreads();
    float bias = LD<BF>(b, lane);
    float a0 = bias, a1 = bias, a2 = bias, a3 = bias;
    #pragma unroll 8
    for (int k = 0; k < 32; k++) {
        float wv = Wl[k * 64 + lane];
        a0 = fmaf(xl[w * 4 + 0][k], wv, a0);
        a1 = fmaf(xl[w * 4 + 1][k], wv, a1);
        a2 = fmaf(xl[w * 4 + 2][k], wv, a2);
        a3 = fmaf(xl[w * 4 + 3][k], wv, a3);
    }
    h[(size_t)(v0 + 0) * 64 + lane] = f2bf(a0);
    h[(size_t)(v0 + 1) * 64 + lane] = f2bf(a1);
    h[(size_t)(v0 + 2) * 64 + lane] = f2bf(a2);
    h[(size_t)(v0 + 3) * 64 + lane] = f2bf(a3);
}

__global__ void k_dense0(const int* __restrict__ flag, const void* x, const void* W,
                         const void* b, unsigned short* h) {
    __shared__ float Wl[32 * 64];
    __shared__ float xl[16][32];
    if (*flag) dense0_body<true>(x, W, b, h, Wl, xl);
    else       dense0_body<false>(x, W, b, h, Wl, xl);
}

// ---------------- aggregation: dual-edge u32 gathers ----------------
// h rows viewed as 32 x u32 (2 bf16 channels/word). Lanes 0-31 take even
// edges, 32-63 odd edges; lane carries channels 2c, 2c+1 (c = lane&31).
// One gather inst = 2 edges (256 B/wave). __shfl_xor(32) merges parities.
// Returns relu'd (ch 2c, ch 2c+1) valid on ALL lanes.

__device__ __forceinline__ float2 agg_node2(int st, int d,
                                            const int* __restrict__ csr_src,
                                            const float* __restrict__ ew,
                                            const unsigned* __restrict__ hu,
                                            int lane) {
    int half = (lane >> 5) & 1;
    int c = lane & 31;
    float a0 = 0.f, a1 = 0.f;
    for (int base = 0; base < d; base += 64) {
        int cnt = min(64, d - base);
        int idx = 0;
        float ev = 0.f;
        if (lane < cnt) {
            idx = csr_src[st + base + lane];
            ev = ew[st + base + lane];
        }
        for (int j = 0; j < cnt; j += 8) {
            #pragma unroll
            for (int p = 0; p < 4; p++) {
                int jj = j + 2 * p + half;            // <= 63 always
                int s = __shfl(idx, jj, 64);          // lanes >= cnt hold idx=0, ev=0
                float e = __shfl(ev, jj, 64);
                unsigned u = hu[(size_t)s * 32 + c];
                a0 = fmaf(e, bf2f((unsigned short)(u & 0xffffu)), a0);
                a1 = fmaf(e, bf2f((unsigned short)(u >> 16)), a1);
            }
        }
    }
    a0 += __shfl_xor(a0, 32, 64);
    a1 += __shfl_xor(a1, 32, 64);
    return make_float2(fmaxf(a0, 0.f), fmaxf(a1, 0.f));   // relu after every agg
}

// ---------------- fused: x = relu(agg(h_in)); h_out = x @ W + b ----------------
// 8 nodes/block (4 waves x 2 nodes); x fp32 in LDS only

template <bool BF>
__device__ __forceinline__ void fuse_body(const int* row_start, const int* deg,
                                          const int* csr_src, const float* ew,
                                          const unsigned* hu,
                                          const void* W, int Woff, const void* b, int boff,
                                          unsigned short* h_out,
                                          float* Wl, float (*xs)[64]) {
    int t = threadIdx.x, w = t >> 6, lane = t & 63;
    for (int i = t; i < 64 * 64; i += 256) Wl[i] = LD<BF>(W, Woff + i);
    int v0 = blockIdx.x * 8 + w * 2;
    #pragma unroll
    for (int n = 0; n < 2; n++) {
        int v = v0 + n;
        float2 r = agg_node2(row_start[v], deg[v], csr_src, ew, hu, lane);
        if (lane < 32) {
            xs[w * 2 + n][lane * 2] = r.x;
            xs[w * 2 + n][lane * 2 + 1] = r.y;
        }
    }
    __syncthreads();
    float bias = LD<BF>(b, boff + lane);
    float a0 = bias, a1 = bias;
    #pragma unroll 8
    for (int k = 0; k < 64; k++) {
        float wv = Wl[k * 64 + lane];
        a0 = fmaf(xs[w * 2 + 0][k], wv, a0);
        a1 = fmaf(xs[w * 2 + 1][k], wv, a1);
    }
    h_out[(size_t)(v0 + 0) * 64 + lane] = f2bf(a0);
    h_out[(size_t)(v0 + 1) * 64 + lane] = f2bf(a1);
}

__global__ void k_fuse(const int* __restrict__ flag,
                       const int* row_start, const int* deg, const int* csr_src,
                       const float* ew, const unsigned* hu,
                       const void* W, int Woff, const void* b, int boff,
                       unsigned short* h_out) {
    __shared__ float Wl[64 * 64];
    __shared__ float xs[8][64];
    if (*flag) fuse_body<true>(row_start, deg, csr_src, ew, hu, W, Woff, b, boff, h_out, Wl, xs);
    else       fuse_body<false>(row_start, deg, csr_src, ew, hu, W, Woff, b, boff, h_out, Wl, xs);
}

// ---------------- fused final: x3 = relu(agg(h3)); heads -> out ---------------
// 16 nodes/block (4 waves x 4 nodes)

template <bool BF>
__device__ __forceinline__ void fuse_heads_body(
        const int* row_start, const int* deg, const int* csr_src,
        const float* ew, const unsigned* hu,
        const void* rh1w, const void* rh1b, const void* rh2w, const void* rh2b,
        const void* meanw, const void* meanb, const void* stdw, const void* stdb,
        const void* cls1w, const void* cls1b, const void* cls2w, const void* cls2b,
        void* __restrict__ out,
        float* s_rh1, float* s_cls1, float* s_rh2, float* s_cls2,
        float* s_rh1b, float* s_cls1b, float* s_rh2b, float* s_mw, float* s_sw,
        float* s_c2b, float* s_msb,
        float (*xs)[64], float (*r1)[32], float (*c1h)[32], float (*r2)[16]) {
    int t = threadIdx.x, w = t >> 6, lane = t & 63;
    for (int i = t; i < 2048; i += 256) { s_rh1[i] = LD<BF>(rh1w, i); s_cls1[i] = LD<BF>(cls1w, i); }
    for (int i = t; i < 512; i += 256) s_rh2[i] = LD<BF>(rh2w, i);
    if (t < 64) s_cls2[t] = LD<BF>(cls2w, t);
    if (t < 32) { s_rh1b[t] = LD<BF>(rh1b, t); s_cls1b[t] = LD<BF>(cls1b, t); }
    else if (t < 48) { int i = t - 32; s_rh2b[i] = LD<BF>(rh2b, i); s_mw[i] = LD<BF>(meanw, i); s_sw[i] = LD<BF>(stdw, i); }
    else if (t == 48) { s_msb[0] = LD<BF>(meanb, 0); s_msb[1] = LD<BF>(stdb, 0); }
    else if (t == 49) { s_c2b[0] = LD<BF>(cls2b, 0); s_c2b[1] = LD<BF>(cls2b, 1); }

    int v00 = blockIdx.x * 16;
    #pragma unroll
    for (int n = 0; n < 4; n++) {
        int idx = w * 4 + n;
        int v = v00 + idx;
        float2 r = agg_node2(row_start[v], deg[v], csr_src, ew, hu, lane);
        if (lane < 32) {
            xs[idx][lane * 2] = r.x;
            xs[idx][lane * 2 + 1] = r.y;
        }
    }
    __syncthreads();

    #pragma unroll
    for (int n = 0; n < 4; n++) {
        int idx = w * 4 + n;
        int c = lane & 31;
        const float* Wp = (lane < 32) ? s_rh1 : s_cls1;
        float acc = (lane < 32) ? s_rh1b[c] : s_cls1b[c];
        #pragma unroll 8
        for (int k = 0; k < 64; k++) acc = fmaf(xs[idx][k], Wp[k * 32 + c], acc);
        acc = fmaxf(acc, 0.f);
        if (lane < 32) r1[idx][c] = acc; else c1h[idx][c] = acc;
    }
    __syncthreads();

    #pragma unroll
    for (int n = 0; n < 4; n++) {
        int idx = w * 4 + n;
        if (lane < 16) {
            float acc = s_rh2b[lane];
            #pragma unroll
            for (int k = 0; k < 32; k++) acc = fmaf(r1[idx][k], s_rh2[k * 16 + lane], acc);
            r2[idx][lane] = fmaxf(acc, 0.f);
        }
    }
    __syncthreads();

    #pragma unroll
    for (int n = 0; n < 4; n++) {
        int idx = w * 4 + n;
        int v = v00 + idx;
        if (lane == 0) {
            float m = s_msb[0];
            #pragma unroll
            for (int k = 0; k < 16; k++) m = fmaf(r2[idx][k], s_mw[k], m);
            if (BF) ((unsigned short*)out)[v] = f2bf(m); else ((float*)out)[v] = m;
        } else if (lane == 1) {
            float sv = s_msb[1];
            #pragma unroll
            for (int k = 0; k < 16; k++) sv = fmaf(r2[idx][k], s_sw[k], sv);
            float sp = fmaxf(sv, 0.f) + log1pf(expf(-fabsf(sv)));   // stable softplus
            if (BF) ((unsigned short*)out)[N_NODES + v] = f2bf(sp); else ((float*)out)[N_NODES + v] = sp;
        } else if (lane < 4) {
            int jj = lane - 2;
            float acc = s_c2b[jj];
            #pragma unroll
            for (int k = 0; k < 32; k++) acc = fmaf(c1h[idx][k], s_cls2[k * 2 + jj], acc);
            size_t pos = (size_t)2 * N_NODES + (size_t)v * 2 + jj;
            if (BF) ((unsigned short*)out)[pos] = f2bf(acc); else ((float*)out)[pos] = acc;
        }
    }
}

__global__ void k_fuse_heads(const int* __restrict__ flag,
                             const int* row_start, const int* deg, const int* csr_src,
                             const float* ew, const unsigned* hu,
                             const void* rh1w, const void* rh1b, const void* rh2w, const void* rh2b,
                             const void* meanw, const void* meanb, const void* stdw, const void* stdb,
                             const void* cls1w, const void* cls1b, const void* cls2w, const void* cls2b,
                             void* out) {
    __shared__ float s_rh1[64 * 32], s_cls1[64 * 32], s_rh2[32 * 16], s_cls2[32 * 2];
    __shared__ float s_rh1b[32], s_cls1b[32], s_rh2b[16], s_mw[16], s_sw[16], s_c2b[2], s_msb[2];
    __shared__ float xs[16][64], r1[16][32], c1h[16][32], r2[16][16];
    if (*flag)
        fuse_heads_body<true>(row_start, deg, csr_src, ew, hu,
                              rh1w, rh1b, rh2w, rh2b, meanw, meanb, stdw, stdb,
                              cls1w, cls1b, cls2w, cls2b, out,
                              s_rh1, s_cls1, s_rh2, s_cls2, s_rh1b, s_cls1b, s_rh2b,
                              s_mw, s_sw, s_c2b, s_msb, xs, r1, c1h, r2);
    else
        fuse_heads_body<false>(row_start, deg, csr_src, ew, hu,
                               rh1w, rh1b, rh2w, rh2b, meanw, meanb, stdw, stdb,
                               cls1w, cls1b, cls2w, cls2b, out,
                               s_rh1, s_cls1, s_rh2, s_cls2, s_rh1b, s_cls1b, s_rh2b,
                               s_mw, s_sw, s_c2b, s_msb, xs, r1, c1h, r2);
}

// ---------------- launch ----------------

extern "C" void kernel_launch(void* const* d_in, const int* in_sizes, int n_in,
                              void* d_out, int out_size, void* d_ws, size_t ws_size,
                              hipStream_t stream) {
    const void* x_in  = d_in[0];
    const int* ei     = (const int*)d_in[1];
    const void* ea    = d_in[2];
    const void* W0    = d_in[3];
    const void* b0    = d_in[4];
    const void* Ws    = d_in[5];
    const void* bs    = d_in[6];
    const void* ew1   = d_in[7];
    const void* eb1   = d_in[8];
    const void* ew2   = d_in[9];
    const void* eb2   = d_in[10];
    const void* rh1w  = d_in[11];
    const void* rh1b  = d_in[12];
    const void* rh2w  = d_in[13];
    const void* rh2b  = d_in[14];
    const void* meanw = d_in[15];
    const void* meanb = d_in[16];
    const void* stdw  = d_in[17];
    const void* stdb  = d_in[18];
    const void* cls1w = d_in[19];
    const void* cls1b = d_in[20];
    const void* cls2w = d_in[21];
    const void* cls2b = d_in[22];

    char* wsp = (char*)d_ws;
    auto alloc = [&](size_t bytes) -> char* {
        char* p = wsp;
        wsp += (bytes + 255) & ~(size_t)255;
        return p;
    };
    // footprint ~65.6 MB (< 78.2 MB proven)
    int* flag       = (int*)alloc(4);
    int* deg        = (int*)alloc((size_t)N_NODES * 4);
    int* row_start  = (int*)alloc((size_t)N_NODES * 4);
    int* cursor     = (int*)alloc((size_t)N_NODES * 4);
    int* bsum       = (int*)alloc((size_t)NB_SCAN * 4);
    int* boff       = (int*)alloc((size_t)NB_SCAN * 4);
    int* csr_src    = (int*)alloc((size_t)N_EDGES * 4);
    float* ew4      = (float*)alloc((size_t)4 * N_EDGES * 4);
    unsigned short* hA = (unsigned short*)alloc((size_t)N_NODES * 64 * 2);
    unsigned short* hB = (unsigned short*)alloc((size_t)N_NODES * 64 * 2);

    k_detect<<<1, 256, 0, stream>>>((const unsigned*)x_in, flag);
    hipMemsetAsync(deg, 0, (size_t)N_NODES * 4, stream);
    k_hist<<<6250, 256, 0, stream>>>(ei, deg);
    k_scan_partial<<<NB_SCAN, 256, 0, stream>>>(deg, bsum);
    k_scan_mid<<<1, 512, 0, stream>>>(bsum, boff);
    k_scan_final<<<NB_SCAN, 256, 0, stream>>>(deg, boff, row_start, cursor);
    k_scatter_ew<<<6250, 256, 0, stream>>>(flag, ei, ea, ew1, eb1, ew2, eb2,
                                           cursor, csr_src, ew4);

    // h0 = x_in @ W0 + b0
    k_dense0<<<6250, 256, 0, stream>>>(flag, x_in, W0, b0, hA);

    unsigned short* hin = hA;
    unsigned short* hout = hB;
    for (int l = 0; l < 3; l++) {
        k_fuse<<<12500, 256, 0, stream>>>(flag, row_start, deg, csr_src,
                                          ew4 + (size_t)l * N_EDGES, (const unsigned*)hin,
                                          Ws, l * 64 * 64, bs, l * 64, hout);
        unsigned short* tmp = hin; hin = hout; hout = tmp;
    }
    k_fuse_heads<<<6250, 256, 0, stream>>>(flag, row_start, deg, csr_src,
                                           ew4 + (size_t)3 * N_EDGES, (const unsigned*)hin,
                                           rh1w, rh1b, rh2w, rh2b, meanw, meanb,
                                           stdw, stdb, cls1w, cls1b, cls2w, cls2b,
                                           d_out);
}